// Round 4
// baseline (448.601 us; speedup 1.0000x reference)
//
#include <hip/hip_runtime.h>
#include <math.h>

#define NB   16
#define HH   209
#define WW   133
#define CIN  64
#define COUT 128
#define OH   201
#define OW   129
#define NTAP 19
#define NW   (NTAP*CIN*COUT)
#define XS   72        // bf16 elems per LDS row (64 + 8 pad)
#define MAXWIN 82      // max staged stride-2 window (f1<=4 -> end<=80, +2 tap shift)
#define NPAIR 101
#define GRID (NB*NPAIR)   // 1616 = 8*202, exact XCD split

typedef __attribute__((ext_vector_type(8))) __bf16 bf16x8;
typedef __attribute__((ext_vector_type(4))) float f32x4;
typedef __attribute__((ext_vector_type(4))) unsigned short us4;

// taps grouped by dh: row dh has c_cnt[dh] taps at c_start[dh]; dw parity == dh parity
__constant__ int c_start[9] = {0, 1, 3, 6, 8, 11, 13, 16, 18};
__constant__ int c_cnt[9]   = {1, 2, 3, 2, 3, 2, 3, 2, 1};
__constant__ int c_k[19]  = {18, 7,17, 6, 8,16, 1, 5, 0, 9,15, 2, 4, 3,10,14, 11,13, 12};
__constant__ int c_dw[19] = { 2, 3, 1, 2, 4, 0, 3, 1, 2, 4, 0, 3, 1, 2, 4, 0, 3, 1, 2};

__device__ __forceinline__ unsigned short f2bf(float f) {
  unsigned int u = __builtin_bit_cast(unsigned int, f);
  u += 0x7FFFu + ((u >> 16) & 1u);       // RNE
  return (unsigned short)(u >> 16);
}

// sparse_weights [ci][co][k] fp32  ->  wt [k][co][ci] bf16
__global__ __launch_bounds__(256) void repack_w(const float* __restrict__ w,
                                                unsigned short* __restrict__ wt) {
  int gid = blockIdx.x * 256 + threadIdx.x;
  int ci = gid & 63;
  int co = (gid >> 6) & 127;
  int k  = gid >> 13;
  wt[gid] = f2bf(w[ci * (COUT * NTAP) + co * NTAP + k]);
}

// One block per (b, output-row-pair oi0=2*pair, oi0+1). 10 staged x-rows serve both
// output rows; row1's taps at staged-row r == row0's taps at r-1 -> B-frag ping-pong reuse.
__global__ __launch_bounds__(256, 2) void conv_hex_mfma(const float* __restrict__ x,
                                                        const unsigned short* __restrict__ wt,
                                                        const float* __restrict__ offs,
                                                        float* __restrict__ out) {
  __shared__ unsigned short xs[2][MAXWIN * XS];   // 2 x 11.8 KB

  const int tid  = threadIdx.x;
  const int lane = tid & 63;
  const int wv   = tid >> 6;
  const int l15  = lane & 15;
  const int quad = lane >> 4;
  const int n0   = wv * 32;

  // XCD swizzle: contiguous work chunks per XCD for x-row L2 locality
  const int bid = blockIdx.x;
  const int wid = (bid & 7) * (GRID / 8) + (bid >> 3);
  const int pair = wid % NPAIR;
  const int b    = wid / NPAIR;
  const int oi0  = pair * 2;                  // even -> row0 par=0, row1 par=1
  const bool has1 = pair < NPAIR - 1;

  // per-row hex ranges: valid iff |oj-64| <= lim
  int ad0 = oi0 - 100; ad0 = ad0 < 0 ? -ad0 : ad0;
  const int lim0 = 128 - ad0;
  int al0 = 64 - lim0; al0 = al0 <= 0 ? 0 : (al0 + 1) >> 1;
  int ah0 = (64 + lim0) >> 1; if (ah0 > 64) ah0 = 64;
  const int f00 = al0 >> 4;
  const int nf0 = (ah0 >> 4) - f00 + 1;       // 1..5
  const int p00 = f00 * 16;

  int lim1 = 0, f01 = 0, nf1 = 0, p01 = p00;
  if (has1) {
    int ad1 = oi0 + 1 - 100; ad1 = ad1 < 0 ? -ad1 : ad1;
    lim1 = 128 - ad1;
    int al1 = 63 - lim1; al1 = al1 <= 0 ? 0 : (al1 + 1) >> 1;
    int ah1 = (63 + lim1) >> 1; if (ah1 > 63) ah1 = 63;
    f01 = al1 >> 4; nf1 = (ah1 >> 4) - f01 + 1; p01 = f01 * 16;
  }

  // union staged window [W, endx) in same-parity units
  const int W = p00 < p01 ? p00 : p01;
  const int e0w = p00 + nf0 * 16, e1w = p01 + nf1 * 16;
  const int endx = (e0w > e1w ? e0w : e1w) + 2;
  const int nwin   = endx - W;                // <= 82
  const int nchunk = nwin * 16;
  const int R = has1 ? 10 : 9;

  const float* xb = x + (size_t)b * (HH * WW * CIN);

  f32x4 acc0[5][2], acc1[5][2];
  #pragma unroll
  for (int i = 0; i < 5; ++i)
    #pragma unroll
    for (int j = 0; j < 2; ++j) {
      acc0[i][j] = (f32x4){0.f, 0.f, 0.f, 0.f};
      acc1[i][j] = (f32x4){0.f, 0.f, 0.f, 0.f};
    }

  float4 stg[6];
  bf16x8 bA[3][2][2], bB[3][2][2];

  auto load_stg = [&](int r) {
    const float* xr = xb + (size_t)(oi0 + r) * (WW * CIN);
    const int cp = r & 1;
    #pragma unroll
    for (int i = 0; i < 6; ++i) {
      int c = tid + i * 256;
      if (c < nchunk) {
        int m = c >> 4, c4 = c & 15;
        int col = cp + 2 * (W + m);
        if (col > WW - 1) col = WW - 1;       // clamp; masked in epilogue
        stg[i] = *(const float4*)(xr + (size_t)col * CIN + c4 * 4);
      }
    }
  };
  auto store_stg = [&](int buf) {
    #pragma unroll
    for (int i = 0; i < 6; ++i) {
      int c = tid + i * 256;
      if (c < nchunk) {
        int m = c >> 4, c4 = c & 15;
        us4 o;
        o.x = f2bf(stg[i].x); o.y = f2bf(stg[i].y);
        o.z = f2bf(stg[i].z); o.w = f2bf(stg[i].w);
        *(us4*)(&xs[buf][m * XS + c4 * 4]) = o;
      }
    }
  };
  auto load_B = [&](bf16x8 (&bf)[3][2][2], int dh) {
    const int st = c_start[dh], cnt = c_cnt[dh];
    #pragma unroll
    for (int t = 0; t < 3; ++t) {
      if (t < cnt) {
        const unsigned short* wb = wt + (size_t)c_k[st + t] * (CIN * COUT)
                                      + (size_t)(n0 + l15) * CIN + quad * 8;
        bf[t][0][0] = *(const bf16x8*)(wb);
        bf[t][1][0] = *(const bf16x8*)(wb + 32);
        bf[t][0][1] = *(const bf16x8*)(wb + 16 * CIN);
        bf[t][1][1] = *(const bf16x8*)(wb + 16 * CIN + 32);
      }
    }
  };
  auto row_compute = [&](const unsigned short* bufp, const bf16x8 (&bf)[3][2][2],
                         int dh, int p0g, int parg, int nfg, int r, f32x4 (&ag)[5][2]) {
    const int st = c_start[dh], cnt = c_cnt[dh];
    #pragma unroll
    for (int t = 0; t < 3; ++t) {
      if (t < cnt) {
        const int dw = c_dw[st + t];
        const int s  = p0g - W + ((parg + dw - (r & 1)) >> 1);
        const unsigned short* ap = bufp + (s + l15) * XS + quad * 8;
        #pragma unroll
        for (int ks = 0; ks < 2; ++ks)
          #pragma unroll
          for (int mf = 0; mf < 5; ++mf)
            if (mf < nfg) {
              bf16x8 a = *(const bf16x8*)(ap + mf * 16 * XS + ks * 32);
              ag[mf][0] = __builtin_amdgcn_mfma_f32_16x16x32_bf16(a, bf[t][ks][0], ag[mf][0], 0, 0, 0);
              ag[mf][1] = __builtin_amdgcn_mfma_f32_16x16x32_bf16(a, bf[t][ks][1], ag[mf][1], 0, 0, 0);
            }
      }
    }
  };

  // prologue
  load_B(bA, 0);
  load_stg(0);
  store_stg(0);

  // K-loop: 2 iterations per pass; bA holds even-dh taps, bB odd-dh.
  // Order inside each iter: barrier -> issue next-row globals -> row1 MFMAs (prev B)
  // -> prefetch next B -> row0 MFMAs (cur B) -> cvt+ds_write (first vmcnt use here).
  #pragma unroll 1
  for (int r = 0; r < 10; r += 2) {
    {
      __syncthreads();                          // buf0 ready
      const unsigned short* bufp = xs[0];
      if (r + 1 < R) load_stg(r + 1);
      if (has1 && r >= 1) row_compute(bufp, bB, r - 1, p01, 1, nf1, r, acc1);
      if (r + 1 <= 8) load_B(bB, r + 1);
      row_compute(bufp, bA, r, p00, 0, nf0, r, acc0);
      if (r + 1 < R) store_stg(1);
    }
    const int ro = r + 1;
    if (ro < R) {
      __syncthreads();                          // buf1 ready
      const unsigned short* bufp = xs[1];
      if (ro + 1 < R) load_stg(ro + 1);
      if (has1) row_compute(bufp, bA, ro - 1, p01, 1, nf1, ro, acc1);
      if (ro + 1 <= 8) load_B(bA, ro + 1);
      if (ro <= 8) row_compute(bufp, bB, ro, p00, 0, nf0, ro, acc0);
      if (ro + 1 < R) store_stg(0);
    }
  }

  // ---- epilogue + zero-fill per row (after loop: no barrier drains these stores) ----
  auto finish_row = [&](int oi_g, int parg, int limg, int f0g, int nfg, f32x4 (&ag)[5][2]) {
    float* outb = out + (size_t)(b * OH + oi_g) * OW * COUT;
    const float4 z = make_float4(0.f, 0.f, 0.f, 0.f);
    const int opar = parg ^ 1;
    const int nopp = 65 - opar;
    for (int idx = tid; idx < nopp * 32; idx += 256) {
      int q = idx >> 5, c4 = idx & 31;
      *(float4*)(outb + (size_t)(opar + 2 * q) * COUT + c4 * 4) = z;
    }
    const int nag = 65 - parg;
    const int p0g = f0g * 16;
    const int hi  = p0g + nfg * 16;
    const int hic = nag > hi ? nag - hi : 0;
    const int tot = (p0g + hic) * 32;
    for (int idx = tid; idx < tot; idx += 256) {
      int q = idx >> 5, c4 = idx & 31;
      int a = q < p0g ? q : hi + (q - p0g);
      *(float4*)(outb + (size_t)(parg + 2 * a) * COUT + c4 * 4) = z;
    }
    const float off0 = offs[n0 + l15];
    const float off1 = offs[n0 + 16 + l15];
    #pragma unroll
    for (int mf = 0; mf < 5; ++mf) {
      if (mf < nfg) {
        #pragma unroll
        for (int rr = 0; rr < 4; ++rr) {
          int a  = (f0g + mf) * 16 + quad * 4 + rr;
          int oj = parg + 2 * a;
          if (oj <= OW - 1) {
            int adj = oj - 64; adj = adj < 0 ? -adj : adj;
            bool valid = adj <= limg;
            float v0 = ag[mf][0][rr] + off0;
            float v1 = ag[mf][1][rr] + off1;
            float e0v = v0 > 0.f ? v0 : expm1f(v0);
            float e1v = v1 > 0.f ? v1 : expm1f(v1);
            outb[(size_t)oj * COUT + n0 + l15]      = valid ? e0v : 0.f;
            outb[(size_t)oj * COUT + n0 + 16 + l15] = valid ? e1v : 0.f;
          }
        }
      }
    }
  };

  finish_row(oi0, 0, lim0, f00, nf0, acc0);
  if (has1) finish_row(oi0 + 1, 1, lim1, f01, nf1, acc1);
}

extern "C" void kernel_launch(void* const* d_in, const int* in_sizes, int n_in,
                              void* d_out, int out_size, void* d_ws, size_t ws_size,
                              hipStream_t stream) {
  const float* x   = (const float*)d_in[0];
  const float* sw  = (const float*)d_in[1];
  const float* off = (const float*)d_in[2];
  float* out = (float*)d_out;

  unsigned short* wtb = (unsigned short*)d_ws;     // 311 KB
  repack_w<<<NW / 256, 256, 0, stream>>>(sw, wtb);
  conv_hex_mfma<<<GRID, 256, 0, stream>>>(x, wtb, off, out);
}